// Round 22
// baseline (204.354 us; speedup 1.0000x reference)
//
#include <hip/hip_runtime.h>
#include <hip/hip_bf16.h>

#define BSZ 16
#define TT 4096
#define UU 128
#define OO 128
#define SS 256
#define HH 512
#define BT (BSZ*TT)      // 65536 rows
#define CLEN 64          // scan chunk length
#define NCH (TT/CLEN)    // 64 chunks per sequence

using bf16x8 = __attribute__((ext_vector_type(8))) short;
using f32x4  = __attribute__((ext_vector_type(4))) float;

__device__ __forceinline__ unsigned short f2bf(float x){
  union { float f; unsigned int u; } v; v.f = x;
  unsigned int r = v.u + 0x7fffu + ((v.u >> 16) & 1u);
  return (unsigned short)(r >> 16);
}
__device__ __forceinline__ float bf2f(unsigned short h){
  union { float f; unsigned int u; } v; v.u = ((unsigned int)h) << 16;
  return v.f;
}

#define GLD16(g, s) __builtin_amdgcn_global_load_lds( \
    (const __attribute__((address_space(1))) unsigned int*)(g), \
    (__attribute__((address_space(3))) unsigned int*)(s), 16, 0, 0)

#define SBAR() do{ __builtin_amdgcn_sched_barrier(0); \
                   __builtin_amdgcn_s_barrier(); \
                   __builtin_amdgcn_sched_barrier(0); }while(0)

// ---------------- split fp32 -> (hi, lo) bf16 planes (input) ----------------
__global__ __launch_bounds__(256) void split_k(const float* __restrict__ x,
                                               unsigned short* __restrict__ H,
                                               unsigned short* __restrict__ L, int n4){
  int i = blockIdx.x * 256 + threadIdx.x;
  if (i >= n4) return;
  float4 v = ((const float4*)x)[i];
  unsigned short h0 = f2bf(v.x), h1 = f2bf(v.y), h2 = f2bf(v.z), h3 = f2bf(v.w);
  ushort4 hh = make_ushort4(h0, h1, h2, h3);
  ushort4 ll = make_ushort4(f2bf(v.x - bf2f(h0)), f2bf(v.y - bf2f(h1)),
                            f2bf(v.z - bf2f(h2)), f2bf(v.w - bf2f(h3)));
  ((ushort4*)H)[i] = hh;
  ((ushort4*)L)[i] = ll;
}

// ---------------- fused 7-weight split ----------------
struct WJobs {
  const float* src[7];
  unsigned short* H[7];
  unsigned short* L[7];
  int end4[7];
};
__global__ __launch_bounds__(256) void split_w(WJobs j, int total4){
  int i = blockIdx.x * 256 + threadIdx.x;
  if (i >= total4) return;
  int t = 0, base = 0;
  #pragma unroll
  for (int k = 0; k < 7; k++){
    if (i >= j.end4[k]){ t = k + 1; base = j.end4[k]; }
  }
  int idx = i - base;
  float4 v = ((const float4*)j.src[t])[idx];
  unsigned short h0 = f2bf(v.x), h1 = f2bf(v.y), h2 = f2bf(v.z), h3 = f2bf(v.w);
  ushort4 hh = make_ushort4(h0, h1, h2, h3);
  ushort4 ll = make_ushort4(f2bf(v.x - bf2f(h0)), f2bf(v.y - bf2f(h1)),
                            f2bf(v.z - bf2f(h2)), f2bf(v.w - bf2f(h3)));
  ((ushort4*)j.H[t])[idx] = hh;
  ((ushort4*)j.L[t])[idx] = ll;
}

// =================== gemm_split: 128x128 2-phase, multi-plane ===================
__global__ __launch_bounds__(256, 2) void gemm_split(
    const unsigned short* __restrict__ AH1, const unsigned short* __restrict__ AL1,
    const unsigned short* __restrict__ BH1, const unsigned short* __restrict__ BL1, int K1, int f1,
    const unsigned short* __restrict__ AH2, const unsigned short* __restrict__ AL2,
    const unsigned short* __restrict__ BH2, const unsigned short* __restrict__ BL2, int K2, int f2,
    unsigned short* __restrict__ outH, unsigned short* __restrict__ outL,
    float* __restrict__ outF, int Nout, int EPI,
    const float* __restrict__ lre, const float* __restrict__ lim,
    float2* __restrict__ ends)
{
  __shared__ __align__(16) unsigned short SM[32768];   // 64 KB
  unsigned short* Ah = SM;            // [2][4096]
  unsigned short* Al = SM + 8192;
  unsigned short* Bh = SM + 16384;
  unsigned short* Bl = SM + 24576;

  const int tid = threadIdx.x;
  const int mb = blockIdx.x, nb = blockIdx.y;
  const int l = tid & 63, w = tid >> 6;
  const int wr = w >> 1, wc = w & 1;
  const int fr = l & 15, fq = l >> 4;

  f32x4 acc[4][4];
  #pragma unroll
  for (int m = 0; m < 4; m++)
    #pragma unroll
    for (int n = 0; n < 4; n++) acc[m][n] = f32x4{0.f, 0.f, 0.f, 0.f};

  const int nkt = (K1 + K2) >> 5;

  auto STAGE = [&](int buf, int kt){
    const int k0 = kt << 5;
    const unsigned short *aH, *aL, *bH, *bL; int st, kk, flg;
    if (k0 < K1){ aH = AH1; aL = AL1; bH = BH1; bL = BL1; st = K1; kk = k0; flg = f1; }
    else        { aH = AH2; aL = AL2; bH = BH2; bL = BL2; st = K2; kk = k0 - K1; flg = f2; }
    #pragma unroll
    for (int it = 0; it < 2; it++){
      int seg = tid + it * 256;
      int r = seg >> 2, c4 = seg & 3;
      int sc = (c4 ^ ((r >> 1) & 3)) << 3;
      size_t go = (size_t)(mb*128 + r) * st + kk + sc;
      size_t gb = (size_t)(nb*128 + r) * st + kk + sc;
      int lo = buf*4096 + r*32 + c4*8;
      GLD16(aH + go, Ah + lo);
      if (flg & 1) GLD16(aL + go, Al + lo);
      GLD16(bH + gb, Bh + lo);
      if (flg & 2) GLD16(bL + gb, Bl + lo);
    }
  };

  STAGE(0, 0);
  __syncthreads();

  for (int kt = 0; kt < nkt; kt++){
    const int cur = kt & 1;
    const int flg = ((kt << 5) < K1) ? f1 : f2;
    if (kt + 1 < nkt) STAGE(cur ^ 1, kt + 1);

    bf16x8 a_h[4], a_l[4], b_h[4], b_l[4];
    #pragma unroll
    for (int m = 0; m < 4; m++){
      int lra = wr*64 + m*16 + fr;
      int ra = cur*4096 + lra*32 + ((fq ^ ((lra >> 1) & 3)) << 3);
      a_h[m] = *(const bf16x8*)&Ah[ra];
      if (flg & 1) a_l[m] = *(const bf16x8*)&Al[ra];
      int lrb = wc*64 + m*16 + fr;
      int rb = cur*4096 + lrb*32 + ((fq ^ ((lrb >> 1) & 3)) << 3);
      b_h[m] = *(const bf16x8*)&Bh[rb];
      if (flg & 2) b_l[m] = *(const bf16x8*)&Bl[rb];
    }
    __builtin_amdgcn_s_setprio(1);
    #pragma unroll
    for (int m = 0; m < 4; m++)
      #pragma unroll
      for (int n = 0; n < 4; n++)
        acc[m][n] = __builtin_amdgcn_mfma_f32_16x16x32_bf16(a_h[m], b_h[n], acc[m][n], 0, 0, 0);
    if (flg & 1)
      #pragma unroll
      for (int m = 0; m < 4; m++)
        #pragma unroll
        for (int n = 0; n < 4; n++)
          acc[m][n] = __builtin_amdgcn_mfma_f32_16x16x32_bf16(a_l[m], b_h[n], acc[m][n], 0, 0, 0);
    if (flg & 2)
      #pragma unroll
      for (int m = 0; m < 4; m++)
        #pragma unroll
        for (int n = 0; n < 4; n++)
          acc[m][n] = __builtin_amdgcn_mfma_f32_16x16x32_bf16(a_h[m], b_l[n], acc[m][n], 0, 0, 0);
    __builtin_amdgcn_s_setprio(0);

    __syncthreads();
  }

  // ---- coalesced epilogue via LDS (128x128 f32 = 64 KB) ----
  float* fl = (float*)SM;
  #pragma unroll
  for (int m = 0; m < 4; m++)
    #pragma unroll
    for (int n = 0; n < 4; n++)
      #pragma unroll
      for (int j = 0; j < 4; j++)
        fl[(wr*64 + m*16 + fq*4 + j)*128 + wc*64 + n*16 + fr] = acc[m][n][j];
  __syncthreads();
  #pragma unroll
  for (int it = 0; it < 8; it++){
    int task = tid + (it << 8);
    int rl = task >> 4, cg = task & 15;
    float4 v0 = *(const float4*)&fl[rl*128 + cg*8];
    float4 v1 = *(const float4*)&fl[rl*128 + cg*8 + 4];
    size_t o = (size_t)(mb*128 + rl) * Nout + nb*128 + cg*8;
    if (EPI == 0){
      *(float4*)(outF + o)     = v0;
      *(float4*)(outF + o + 4) = v1;
    } else {
      float xv[8] = {v0.x,v0.y,v0.z,v0.w,v1.x,v1.y,v1.z,v1.w};
      union { unsigned short us[8]; uint4 v; } ph, pl;
      #pragma unroll
      for (int e = 0; e < 8; e++){
        float x = xv[e];
        if (EPI == 2)      x = x / (1.f + __expf(-x));
        else if (EPI == 3) x = fmaxf(x, 0.f);
        ph.us[e] = f2bf(x);
        pl.us[e] = f2bf(x - bf2f(ph.us[e]));
      }
      *(uint4*)(outH + o) = ph.v;
      if (outL) *(uint4*)(outL + o) = pl.v;
    }
  }
  // ---- fused chunk-ends scan (bu only): fp32 values, pre-rounding ----
  if (ends){
    int c = tid >> 7, sl = tid & 127;          // 2 chunks x 128 s-cols
    int b = mb >> 5, chunk = ((mb & 31) << 1) + c;
    int s = nb*128 + sl;
    float lr = lre[s], li = lim[s];
    float hr = 0.f, hi2 = 0.f;
    for (int t = 0; t < 64; t++){
      float x = fl[(c*64 + t)*128 + sl];
      float nr = fmaf(lr, hr, fmaf(-li, hi2, x));
      float ni = fmaf(lr, hi2, li * hr);
      hr = nr; hi2 = ni;
    }
    ends[((size_t)(b*NCH + chunk))*SS + s] = make_float2(hr, hi2);
  }
}

// =================== mlp_fused v6: v5 + full unroll of phase loops ===================
// (r21 diagnosis: VALUBusy 30% > MfmaUtil 26% with VGPR=52 -> compiler left the
// 16-step loops rolled; every k-step recomputed %3 slots + addresses. Full
// unroll folds kt, kt%3, and all offsets into immediates. Pipeline semantics
// identical: per-iteration vmcnt + sched_barrier preserved.)
#define RING_OFF 65536

__global__ __launch_bounds__(1024, 1) void mlp_fused(
    const unsigned short* __restrict__ yH,
    const unsigned short* __restrict__ inH, const unsigned short* __restrict__ inL,
    const unsigned short* __restrict__ W1H, const unsigned short* __restrict__ W2H,
    const unsigned short* __restrict__ W3H, const unsigned short* __restrict__ W3L,
    const unsigned short* __restrict__ WlH, const unsigned short* __restrict__ WlL,
    float* __restrict__ out)
{
  __shared__ __align__(16) unsigned char LDS[163840];   // 160 KB
  const int tid = threadIdx.x;
  const int l = tid & 63, w = tid >> 6;      // 16 waves
  const int fr = l & 15, fq = l >> 4;
  const int mh = w >> 3, nf = w & 7;         // phase A2/C mapping
  const size_t r0 = (size_t)blockIdx.x * 64;
  const int ringb = RING_OFF + w*6144;

  // ---- 32-row stage (W1 / W2): rows w*32..+32, 2 GLD/thread ----
  auto stage32 = [&](const unsigned short* W, int strideK, int kt){
    const int so = (kt % 3) * 2048;
    #pragma unroll
    for (int it = 0; it < 2; it++){
      int seg = l + (it << 6);               // [32 rows][4 chunks]
      int r = seg >> 2, c4 = seg & 3;
      GLD16(W + (size_t)(w*32 + r) * strideK + kt*32 + ((c4 ^ ((r >> 1) & 3)) << 3),
            LDS + ringb + so + seg*16);
    }
  };
  // ---- H+L pair stage (Wl / W3): rows nf*16..+16, 2 planes, 2 GLD/thread ----
  auto stagePair = [&](const unsigned short* PH, const unsigned short* PL, int strideK, int kt){
    const int so = (kt % 3) * 2048;
    #pragma unroll
    for (int it = 0; it < 2; it++){
      int seg = l + (it << 6);               // [2 planes][16 rows][4 chunks]
      const unsigned short* P = (seg >> 6) ? PL : PH;
      int rr = (seg >> 2) & 15, c4 = seg & 3;
      GLD16(P + (size_t)(nf*16 + rr) * strideK + kt*32 + ((c4 ^ ((rr >> 1) & 3)) << 3),
            LDS + ringb + so + seg*16);
    }
  };

  // ---- prologue: stage Y@0, inH@16K, inL@32K (1 GLD each), W1 ring 0,1 ----
  {
    int r = tid >> 4, c16 = tid & 15;
    int sc = (c16 ^ (r & 7)) << 3;
    GLD16(yH  + (size_t)(r0 + r) * UU + sc, LDS + tid*16);
    GLD16(inH + (size_t)(r0 + r) * UU + sc, LDS + 16384 + tid*16);
    GLD16(inL + (size_t)(r0 + r) * UU + sc, LDS + 32768 + tid*16);
  }
  stage32(W1H, UU, 0);
  stage32(W1H, UU, 1);
  asm volatile("s_waitcnt vmcnt(4)" ::: "memory");   // Y/inH/inL (oldest) complete
  SBAR();                                    // [b1]

  f32x4 acc[4][2];
  #pragma unroll
  for (int m = 0; m < 4; m++)
    #pragma unroll
    for (int n = 0; n < 2; n++) acc[m][n] = f32x4{0.f, 0.f, 0.f, 0.f};

  // ======== phase A1: z1 = silu(y @ W1^T), 4 k-steps, barrier-free ========
  #pragma unroll
  for (int kt = 0; kt < 4; kt++){
    if (kt < 3) asm volatile("s_waitcnt vmcnt(2)" ::: "memory");
    else        asm volatile("s_waitcnt vmcnt(0)" ::: "memory");
    __builtin_amdgcn_sched_barrier(0);
    const unsigned char* Wb = LDS + ringb + (kt % 3)*2048;
    bf16x8 a[4], b[2];
    #pragma unroll
    for (int m = 0; m < 4; m++){
      int row = m*16 + fr, kc = kt*4 + fq;
      a[m] = *(const bf16x8*)(LDS + (row*128 + ((kc ^ (row & 7)) << 3))*2);
    }
    #pragma unroll
    for (int n = 0; n < 2; n++){
      int rl = n*16 + fr;
      b[n] = *(const bf16x8*)(Wb + rl*64 + ((fq ^ ((rl >> 1) & 3)) << 4));
    }
    __builtin_amdgcn_s_setprio(1);
    #pragma unroll
    for (int m = 0; m < 4; m++)
      #pragma unroll
      for (int n = 0; n < 2; n++)
        acc[m][n] = __builtin_amdgcn_mfma_f32_16x16x32_bf16(a[m], b[n], acc[m][n], 0, 0, 0);
    __builtin_amdgcn_s_setprio(0);
    if (kt + 2 < 4) stage32(W1H, UU, kt + 2);
  }

  // ======== phase A2: acc_o = in @ Wl^T (3-term), 4 k-steps, barrier-free ========
  f32x4 acc_o[2];
  acc_o[0] = f32x4{0.f, 0.f, 0.f, 0.f};
  acc_o[1] = f32x4{0.f, 0.f, 0.f, 0.f};
  stagePair(WlH, WlL, UU, 0);
  stagePair(WlH, WlL, UU, 1);
  #pragma unroll
  for (int kt = 0; kt < 4; kt++){
    if (kt < 3) asm volatile("s_waitcnt vmcnt(2)" ::: "memory");
    else        asm volatile("s_waitcnt vmcnt(0)" ::: "memory");
    __builtin_amdgcn_sched_barrier(0);
    const unsigned char* Wb = LDS + ringb + (kt % 3)*2048;
    bf16x8 ah[2], al[2], bh, bl;
    #pragma unroll
    for (int m = 0; m < 2; m++){
      int row = mh*32 + m*16 + fr, kc = kt*4 + fq;
      int off = (row*128 + ((kc ^ (row & 7)) << 3))*2;
      ah[m] = *(const bf16x8*)(LDS + 16384 + off);
      al[m] = *(const bf16x8*)(LDS + 32768 + off);
    }
    {
      int rl = fr;
      int boff = rl*64 + ((fq ^ ((rl >> 1) & 3)) << 4);
      bh = *(const bf16x8*)(Wb + boff);
      bl = *(const bf16x8*)(Wb + 1024 + boff);
    }
    __builtin_amdgcn_s_setprio(1);
    #pragma unroll
    for (int m = 0; m < 2; m++){
      acc_o[m] = __builtin_amdgcn_mfma_f32_16x16x32_bf16(ah[m], bh, acc_o[m], 0, 0, 0);
      acc_o[m] = __builtin_amdgcn_mfma_f32_16x16x32_bf16(al[m], bh, acc_o[m], 0, 0, 0);
      acc_o[m] = __builtin_amdgcn_mfma_f32_16x16x32_bf16(ah[m], bl, acc_o[m], 0, 0, 0);
    }
    __builtin_amdgcn_s_setprio(0);
    if (kt + 2 < 4) stagePair(WlH, WlL, UU, kt + 2);
  }
  SBAR();                                    // [b2] all Y/in reads done

  // W2 prologue stages (wave-private; latency hides under z1 silu/writes)
  stage32(W2H, HH, 0);
  stage32(W2H, HH, 1);

  // ---- silu + write z1 -> Z1T [kchunk][row][8] (K-major) @0 ----
  unsigned short* Z1 = (unsigned short*)LDS;
  #pragma unroll
  for (int m = 0; m < 4; m++)
    #pragma unroll
    for (int n = 0; n < 2; n++)
      #pragma unroll
      for (int j = 0; j < 4; j++){
        float x = acc[m][n][j];
        x = x / (1.f + __expf(-x));          // silu
        int row = m*16 + fq*4 + j;
        int col = w*32 + n*16 + fr;
        Z1[(col >> 3)*512 + row*8 + (col & 7)] = f2bf(x);
      }
  SBAR();                                    // [b3] z1 visible

  // ======== phase B: z2 = relu(z1 @ W2^T), 16 k-steps, barrier-free ========
  #pragma unroll
  for (int m = 0; m < 4; m++)
    #pragma unroll
    for (int n = 0; n < 2; n++) acc[m][n] = f32x4{0.f, 0.f, 0.f, 0.f};

  #pragma unroll
  for (int kt = 0; kt < 16; kt++){
    if (kt < 15) asm volatile("s_waitcnt vmcnt(2)" ::: "memory");
    else         asm volatile("s_waitcnt vmcnt(0)" ::: "memory");
    __builtin_amdgcn_sched_barrier(0);
    const unsigned char* Wb = LDS + ringb + (kt % 3)*2048;
    bf16x8 a[4], b[2];
    #pragma unroll
    for (int m = 0; m < 4; m++)
      a[m] = *(const bf16x8*)(LDS + (size_t)(kt*4 + fq)*1024 + (m*16 + fr)*16);
    #pragma unroll
    for (int n = 0; n < 2; n++){
      int rl = n*16 + fr;
      b[n] = *(const bf16x8*)(Wb + rl*64 + ((fq ^ ((rl >> 1) & 3)) << 4));
    }
    __builtin_amdgcn_s_setprio(1);
    #pragma unroll
    for (int m = 0; m < 4; m++)
      #pragma unroll
      for (int n = 0; n < 2; n++)
        acc[m][n] = __builtin_amdgcn_mfma_f32_16x16x32_bf16(a[m], b[n], acc[m][n], 0, 0, 0);
    __builtin_amdgcn_s_setprio(0);
    if (kt + 2 < 16) stage32(W2H, HH, kt + 2);
  }

  // W3 prologue stages (own ring, freed by vmcnt(0) above)
  stagePair(W3H, W3L, HH, 0);
  stagePair(W3H, W3L, HH, 1);
  SBAR();                                    // [b4] all Z1T reads done

  // ---- relu + write z2 -> Z2T [kchunk][row][8] @0 (bf16 rounding as before) ----
  unsigned short* Z2 = (unsigned short*)LDS;
  #pragma unroll
  for (int m = 0; m < 4; m++)
    #pragma unroll
    for (int n = 0; n < 2; n++)
      #pragma unroll
      for (int j = 0; j < 4; j++){
        float x = fmaxf(acc[m][n][j], 0.f);  // relu
        int row = m*16 + fq*4 + j;
        int col = w*32 + n*16 + fr;
        Z2[(col >> 3)*512 + row*8 + (col & 7)] = f2bf(x);
      }
  SBAR();                                    // [b5] z2 visible

  // ======== phase C: acc_o += z2 @ W3^T (2-term), 16 k-steps, barrier-free ========
  #pragma unroll
  for (int kt = 0; kt < 16; kt++){
    if (kt < 15) asm volatile("s_waitcnt vmcnt(2)" ::: "memory");
    else         asm volatile("s_waitcnt vmcnt(0)" ::: "memory");
    __builtin_amdgcn_sched_barrier(0);
    const unsigned char* Wb = LDS + ringb + (kt % 3)*2048;
    bf16x8 a[2], bh, bl;
    #pragma unroll
    for (int m = 0; m < 2; m++)
      a[m] = *(const bf16x8*)(LDS + (size_t)(kt*4 + fq)*1024 + (mh*32 + m*16 + fr)*16);
    {
      int rl = fr;
      int boff = rl*64 + ((fq ^ ((rl >> 1) & 3)) << 4);
      bh = *(const bf16x8*)(Wb + boff);
      bl = *(const bf16x8*)(Wb + 1024 + boff);
    }
    __builtin_amdgcn_s_setprio(1);
    #pragma unroll
    for (int m = 0; m < 2; m++){
      acc_o[m] = __builtin_amdgcn_mfma_f32_16x16x32_bf16(a[m], bh, acc_o[m], 0, 0, 0);
      acc_o[m] = __builtin_amdgcn_mfma_f32_16x16x32_bf16(a[m], bl, acc_o[m], 0, 0, 0);
    }
    __builtin_amdgcn_s_setprio(0);
    if (kt + 2 < 16) stagePair(W3H, W3L, HH, kt + 2);
  }
  SBAR();                                    // [b6] rings free for EP reuse

  // ---- fp32 epilogue via LDS (64x128 f32 = 32 KB @RING_OFF) ----
  float* EP = (float*)(LDS + RING_OFF);
  #pragma unroll
  for (int m = 0; m < 2; m++)
    #pragma unroll
    for (int j = 0; j < 4; j++)
      EP[(mh*32 + m*16 + fq*4 + j)*128 + nf*16 + fr] = acc_o[m][j];
  __syncthreads();
  #pragma unroll
  for (int it = 0; it < 2; it++){
    int seg = tid + (it << 10);              // 2048 float4 = [64 rows][32 groups]
    int r = seg >> 5, c4 = seg & 31;
    *(float4*)(out + (r0 + r)*OO + c4*4) = *(const float4*)(EP + r*128 + c4*4);
  }
}

// ---------------- scan carries ----------------
__global__ __launch_bounds__(256) void scan_carries(const float2* __restrict__ ends,
                                                    const float* __restrict__ lre,
                                                    const float* __restrict__ lim,
                                                    float2* __restrict__ carryin){
  const int idx = blockIdx.x * 256 + threadIdx.x;
  const int b = idx >> 8;
  const int s = idx & 255;
  float pr = lre[s], pi = lim[s];
  #pragma unroll
  for (int q = 0; q < 6; q++){
    float nr = pr*pr - pi*pi;
    float ni = 2.f * pr * pi;
    pr = nr; pi = ni;
  }
  float hr = 0.f, hi = 0.f;
  for (int c = 0; c < NCH; c++){
    size_t o = ((size_t)b*NCH + c)*SS + s;
    carryin[o] = make_float2(hr, hi);
    float2 e = ends[o];
    float nr = fmaf(pr, hr, fmaf(-pi, hi, e.x));
    float ni = fmaf(pr, hi, fmaf(pi, hr, e.y));
    hr = nr; hi = ni;
  }
}

// ---------------- scan apply: vectorized, RehH (bf16) only ----------------
__global__ __launch_bounds__(256) void scan_apply_v(
    const unsigned short* __restrict__ buH, const unsigned short* __restrict__ buL,
    const float* __restrict__ lre, const float* __restrict__ lim,
    const float2* __restrict__ carryin, unsigned short* __restrict__ RehH){
  const int tid = threadIdx.x;
  const int grp = tid >> 6, ln = tid & 63;
  const int chunk = blockIdx.x * 4 + grp;         // 0..1023
  const int b = chunk >> 6, ch = chunk & 63;
  const int s0 = ln * 4;
  float lr[4], li[4], hr[4], hi[4];
  #pragma unroll
  for (int e = 0; e < 4; e++){ lr[e] = lre[s0+e]; li[e] = lim[s0+e]; }
  const float2* ci = &carryin[((size_t)(b*NCH + ch))*SS + s0];
  #pragma unroll
  for (int e = 0; e < 4; e++){ hr[e] = ci[e].x; hi[e] = ci[e].y; }
  const size_t rbase = ((size_t)b*TT + (size_t)ch*CLEN)*SS + s0;
  for (int t = 0; t < CLEN; t++){
    uint2 hv = *(const uint2*)(buH + rbase + (size_t)t*SS);
    uint2 lv = *(const uint2*)(buL + rbase + (size_t)t*SS);
    const unsigned short* hs = (const unsigned short*)&hv;
    const unsigned short* ls = (const unsigned short*)&lv;
    uint2 ov; unsigned short* os = (unsigned short*)&ov;
    #pragma unroll
    for (int e = 0; e < 4; e++){
      float x = bf2f(hs[e]) + bf2f(ls[e]);
      float nr = fmaf(lr[e], hr[e], fmaf(-li[e], hi[e], x));
      float ni = fmaf(lr[e], hi[e], li[e] * hr[e]);
      hr[e] = nr; hi[e] = ni;
      os[e] = f2bf(nr);
    }
    *(uint2*)(RehH + rbase + (size_t)t*SS) = ov;
  }
}

extern "C" void kernel_launch(void* const* d_in, const int* in_sizes, int n_in,
                              void* d_out, int out_size, void* d_ws, size_t ws_size,
                              hipStream_t stream){
  const float* inp = (const float*)d_in[0];
  const float* lre = (const float*)d_in[1];
  const float* lim = (const float*)d_in[2];
  const float* Bm  = (const float*)d_in[3];
  const float* Cm  = (const float*)d_in[4];
  const float* Dm  = (const float*)d_in[5];
  const float* W1  = (const float*)d_in[6];
  const float* W2  = (const float*)d_in[7];
  const float* W3  = (const float*)d_in[8];
  const float* Wl  = (const float*)d_in[9];
  float* out = (float*)d_out;

  char* ws = (char*)d_ws;
  size_t off = 0;
  auto alloc = [&](size_t bytes)->char*{
    char* p = ws + off; off += (bytes + 255) & ~(size_t)255; return p;
  };
  // ---- region-reused workspace plan ----
  unsigned short* inH  = (unsigned short*)alloc((size_t)BT*UU*2);   // live all
  unsigned short* inL  = (unsigned short*)alloc((size_t)BT*UU*2);   // live all
  char* Rbu = alloc((size_t)BT*SS*2*2);                             // buH+buL
  unsigned short* buH = (unsigned short*)Rbu;
  unsigned short* buL = (unsigned short*)(Rbu + (size_t)BT*SS*2);
  char* R2 = alloc((size_t)BT*HH*2);                                // RehH+yH
  unsigned short* RehH = (unsigned short*)R2;
  unsigned short* yH   = (unsigned short*)(R2 + (size_t)BT*SS*2);
  unsigned short* BwH = (unsigned short*)alloc((size_t)SS*UU*2);
  unsigned short* BwL = (unsigned short*)alloc((size_t)SS*UU*2);
  unsigned short* CH_ = (unsigned short*)alloc((size_t)OO*SS*2);
  unsigned short* CL_ = (unsigned short*)alloc((size_t)OO*SS*2);
  unsigned short* DH_ = (unsigned short*)alloc((size_t)OO*UU*2);
  unsigned short* DL_ = (unsigned short*)alloc((size_t)OO*UU*2);
  unsigned short* W1H = (unsigned short*)alloc((size_t)HH*OO*2);
  unsigned short* W1L = (unsigned short*)alloc((size_t)HH*OO*2);
  unsigned short* W2H = (unsigned short*)alloc((size_t)HH*HH*2);
  unsigned short* W2L = (unsigned short*)alloc((size_t)HH*HH*2);
  unsigned short* W3H = (unsigned short*)alloc((size_t)OO*HH*2);
  unsigned short* W3L = (unsigned short*)alloc((size_t)OO*HH*2);
  unsigned short* WlH = (unsigned short*)alloc((size_t)OO*UU*2);
  unsigned short* WlL = (unsigned short*)alloc((size_t)OO*UU*2);
  float2* ends    = (float2*)alloc((size_t)BSZ*NCH*SS*8);
  float2* carryin = (float2*)alloc((size_t)BSZ*NCH*SS*8);
  if (off > ws_size) return;

  // ---- splits ----
  split_k<<<(BT*UU/4 + 255)/256, 256, 0, stream>>>(inp, inH, inL, BT*UU/4);
  {
    WJobs j;
    const float* srcs[7] = {Bm, Cm, Dm, W1, W2, W3, Wl};
    unsigned short* Hs[7] = {BwH, CH_, DH_, W1H, W2H, W3H, WlH};
    unsigned short* Ls[7] = {BwL, CL_, DL_, W1L, W2L, W3L, WlL};
    int n4s[7] = {SS*UU/4, OO*SS/4, OO*UU/4, HH*OO/4, HH*HH/4, OO*HH/4, OO*UU/4};
    int cum = 0;
    for (int k = 0; k < 7; k++){
      j.src[k] = srcs[k]; j.H[k] = Hs[k]; j.L[k] = Ls[k];
      cum += n4s[k]; j.end4[k] = cum;
    }
    split_w<<<(cum + 255)/256, 256, 0, stream>>>(j, cum);
  }

  // ---- bu = input @ B^T (3-term), H/L out + fused chunk-end scans ----
  gemm_split<<<dim3(BT/128, SS/128), 256, 0, stream>>>(
      inH, inL, BwH, BwL, UU, 3,
      inH, inL, BwH, BwL, 0,  3,
      buH, buL, nullptr, SS, 1,
      lre, lim, ends);

  // ---- cross-chunk carries ----
  scan_carries<<<(BSZ*SS)/256, 256, 0, stream>>>(ends, lre, lim, carryin);

  // ---- scan apply -> RehH (bf16 only) ----
  scan_apply_v<<<BSZ*NCH/4, 256, 0, stream>>>(buH, buL, lre, lim, carryin, RehH);

  // ---- y = Reh@C^T (2-term: C hi+lo) + in@D^T (3-term); yH only ----
  gemm_split<<<dim3(BT/128, OO/128), 256, 0, stream>>>(
      RehH, RehH, CH_, CL_, SS, 2,
      inH,  inL,  DH_, DL_, UU, 3,
      yH, nullptr, nullptr, OO, 1,
      nullptr, nullptr, nullptr);

  // ---- out = relu(silu(y@W1^T)@W2^T)@W3^T + in@Wl^T : fully fused ----
  mlp_fused<<<BT/64, 1024, 0, stream>>>(yH, inH, inL, W1H, W2H, W3H, W3L,
                                        WlH, WlL, out);
}

// Round 23
// 200.129 us; speedup vs baseline: 1.0211x; 1.0211x over previous
//
#include <hip/hip_runtime.h>
#include <hip/hip_bf16.h>

#define BSZ 16
#define TT 4096
#define UU 128
#define OO 128
#define SS 256
#define HH 512
#define BT (BSZ*TT)      // 65536 rows
#define CLEN 64          // scan chunk length
#define NCH (TT/CLEN)    // 64 chunks per sequence

using bf16x8 = __attribute__((ext_vector_type(8))) short;
using f32x4  = __attribute__((ext_vector_type(4))) float;

__device__ __forceinline__ unsigned short f2bf(float x){
  union { float f; unsigned int u; } v; v.f = x;
  unsigned int r = v.u + 0x7fffu + ((v.u >> 16) & 1u);
  return (unsigned short)(r >> 16);
}
__device__ __forceinline__ float bf2f(unsigned short h){
  union { float f; unsigned int u; } v; v.u = ((unsigned int)h) << 16;
  return v.f;
}

#define GLD16(g, s) __builtin_amdgcn_global_load_lds( \
    (const __attribute__((address_space(1))) unsigned int*)(g), \
    (__attribute__((address_space(3))) unsigned int*)(s), 16, 0, 0)

#define SBAR() do{ __builtin_amdgcn_sched_barrier(0); \
                   __builtin_amdgcn_s_barrier(); \
                   __builtin_amdgcn_sched_barrier(0); }while(0)

// ---------------- split fp32 -> (hi, lo) bf16 planes (input) ----------------
__global__ __launch_bounds__(256) void split_k(const float* __restrict__ x,
                                               unsigned short* __restrict__ H,
                                               unsigned short* __restrict__ L, int n4){
  int i = blockIdx.x * 256 + threadIdx.x;
  if (i >= n4) return;
  float4 v = ((const float4*)x)[i];
  unsigned short h0 = f2bf(v.x), h1 = f2bf(v.y), h2 = f2bf(v.z), h3 = f2bf(v.w);
  ushort4 hh = make_ushort4(h0, h1, h2, h3);
  ushort4 ll = make_ushort4(f2bf(v.x - bf2f(h0)), f2bf(v.y - bf2f(h1)),
                            f2bf(v.z - bf2f(h2)), f2bf(v.w - bf2f(h3)));
  ((ushort4*)H)[i] = hh;
  ((ushort4*)L)[i] = ll;
}

// ---------------- fused 7-weight split ----------------
struct WJobs {
  const float* src[7];
  unsigned short* H[7];
  unsigned short* L[7];
  int end4[7];
};
__global__ __launch_bounds__(256) void split_w(WJobs j, int total4){
  int i = blockIdx.x * 256 + threadIdx.x;
  if (i >= total4) return;
  int t = 0, base = 0;
  #pragma unroll
  for (int k = 0; k < 7; k++){
    if (i >= j.end4[k]){ t = k + 1; base = j.end4[k]; }
  }
  int idx = i - base;
  float4 v = ((const float4*)j.src[t])[idx];
  unsigned short h0 = f2bf(v.x), h1 = f2bf(v.y), h2 = f2bf(v.z), h3 = f2bf(v.w);
  ushort4 hh = make_ushort4(h0, h1, h2, h3);
  ushort4 ll = make_ushort4(f2bf(v.x - bf2f(h0)), f2bf(v.y - bf2f(h1)),
                            f2bf(v.z - bf2f(h2)), f2bf(v.w - bf2f(h3)));
  ((ushort4*)j.H[t])[idx] = hh;
  ((ushort4*)j.L[t])[idx] = ll;
}

// =================== gemm_split: 128x128 2-phase, multi-plane ===================
__global__ __launch_bounds__(256, 2) void gemm_split(
    const unsigned short* __restrict__ AH1, const unsigned short* __restrict__ AL1,
    const unsigned short* __restrict__ BH1, const unsigned short* __restrict__ BL1, int K1, int f1,
    const unsigned short* __restrict__ AH2, const unsigned short* __restrict__ AL2,
    const unsigned short* __restrict__ BH2, const unsigned short* __restrict__ BL2, int K2, int f2,
    unsigned short* __restrict__ outH, unsigned short* __restrict__ outL,
    float* __restrict__ outF, int Nout, int EPI,
    const float* __restrict__ lre, const float* __restrict__ lim,
    float2* __restrict__ ends)
{
  __shared__ __align__(16) unsigned short SM[32768];   // 64 KB
  unsigned short* Ah = SM;            // [2][4096]
  unsigned short* Al = SM + 8192;
  unsigned short* Bh = SM + 16384;
  unsigned short* Bl = SM + 24576;

  const int tid = threadIdx.x;
  const int mb = blockIdx.x, nb = blockIdx.y;
  const int l = tid & 63, w = tid >> 6;
  const int wr = w >> 1, wc = w & 1;
  const int fr = l & 15, fq = l >> 4;

  f32x4 acc[4][4];
  #pragma unroll
  for (int m = 0; m < 4; m++)
    #pragma unroll
    for (int n = 0; n < 4; n++) acc[m][n] = f32x4{0.f, 0.f, 0.f, 0.f};

  const int nkt = (K1 + K2) >> 5;

  auto STAGE = [&](int buf, int kt){
    const int k0 = kt << 5;
    const unsigned short *aH, *aL, *bH, *bL; int st, kk, flg;
    if (k0 < K1){ aH = AH1; aL = AL1; bH = BH1; bL = BL1; st = K1; kk = k0; flg = f1; }
    else        { aH = AH2; aL = AL2; bH = BH2; bL = BL2; st = K2; kk = k0 - K1; flg = f2; }
    #pragma unroll
    for (int it = 0; it < 2; it++){
      int seg = tid + it * 256;
      int r = seg >> 2, c4 = seg & 3;
      int sc = (c4 ^ ((r >> 1) & 3)) << 3;
      size_t go = (size_t)(mb*128 + r) * st + kk + sc;
      size_t gb = (size_t)(nb*128 + r) * st + kk + sc;
      int lo = buf*4096 + r*32 + c4*8;
      GLD16(aH + go, Ah + lo);
      if (flg & 1) GLD16(aL + go, Al + lo);
      GLD16(bH + gb, Bh + lo);
      if (flg & 2) GLD16(bL + gb, Bl + lo);
    }
  };

  STAGE(0, 0);
  __syncthreads();

  for (int kt = 0; kt < nkt; kt++){
    const int cur = kt & 1;
    const int flg = ((kt << 5) < K1) ? f1 : f2;
    if (kt + 1 < nkt) STAGE(cur ^ 1, kt + 1);

    bf16x8 a_h[4], a_l[4], b_h[4], b_l[4];
    #pragma unroll
    for (int m = 0; m < 4; m++){
      int lra = wr*64 + m*16 + fr;
      int ra = cur*4096 + lra*32 + ((fq ^ ((lra >> 1) & 3)) << 3);
      a_h[m] = *(const bf16x8*)&Ah[ra];
      if (flg & 1) a_l[m] = *(const bf16x8*)&Al[ra];
      int lrb = wc*64 + m*16 + fr;
      int rb = cur*4096 + lrb*32 + ((fq ^ ((lrb >> 1) & 3)) << 3);
      b_h[m] = *(const bf16x8*)&Bh[rb];
      if (flg & 2) b_l[m] = *(const bf16x8*)&Bl[rb];
    }
    __builtin_amdgcn_s_setprio(1);
    #pragma unroll
    for (int m = 0; m < 4; m++)
      #pragma unroll
      for (int n = 0; n < 4; n++)
        acc[m][n] = __builtin_amdgcn_mfma_f32_16x16x32_bf16(a_h[m], b_h[n], acc[m][n], 0, 0, 0);
    if (flg & 1)
      #pragma unroll
      for (int m = 0; m < 4; m++)
        #pragma unroll
        for (int n = 0; n < 4; n++)
          acc[m][n] = __builtin_amdgcn_mfma_f32_16x16x32_bf16(a_l[m], b_h[n], acc[m][n], 0, 0, 0);
    if (flg & 2)
      #pragma unroll
      for (int m = 0; m < 4; m++)
        #pragma unroll
        for (int n = 0; n < 4; n++)
          acc[m][n] = __builtin_amdgcn_mfma_f32_16x16x32_bf16(a_h[m], b_l[n], acc[m][n], 0, 0, 0);
    __builtin_amdgcn_s_setprio(0);

    __syncthreads();
  }

  // ---- coalesced epilogue via LDS (128x128 f32 = 64 KB) ----
  float* fl = (float*)SM;
  #pragma unroll
  for (int m = 0; m < 4; m++)
    #pragma unroll
    for (int n = 0; n < 4; n++)
      #pragma unroll
      for (int j = 0; j < 4; j++)
        fl[(wr*64 + m*16 + fq*4 + j)*128 + wc*64 + n*16 + fr] = acc[m][n][j];
  __syncthreads();
  #pragma unroll
  for (int it = 0; it < 8; it++){
    int task = tid + (it << 8);
    int rl = task >> 4, cg = task & 15;
    float4 v0 = *(const float4*)&fl[rl*128 + cg*8];
    float4 v1 = *(const float4*)&fl[rl*128 + cg*8 + 4];
    size_t o = (size_t)(mb*128 + rl) * Nout + nb*128 + cg*8;
    if (EPI == 0){
      *(float4*)(outF + o)     = v0;
      *(float4*)(outF + o + 4) = v1;
    } else {
      float xv[8] = {v0.x,v0.y,v0.z,v0.w,v1.x,v1.y,v1.z,v1.w};
      union { unsigned short us[8]; uint4 v; } ph, pl;
      #pragma unroll
      for (int e = 0; e < 8; e++){
        float x = xv[e];
        if (EPI == 2)      x = x / (1.f + __expf(-x));
        else if (EPI == 3) x = fmaxf(x, 0.f);
        ph.us[e] = f2bf(x);
        pl.us[e] = f2bf(x - bf2f(ph.us[e]));
      }
      *(uint4*)(outH + o) = ph.v;
      if (outL) *(uint4*)(outL + o) = pl.v;
    }
  }
  // ---- fused chunk-ends scan (bu only): fp32 values, pre-rounding ----
  if (ends){
    int c = tid >> 7, sl = tid & 127;          // 2 chunks x 128 s-cols
    int b = mb >> 5, chunk = ((mb & 31) << 1) + c;
    int s = nb*128 + sl;
    float lr = lre[s], li = lim[s];
    float hr = 0.f, hi2 = 0.f;
    for (int t = 0; t < 64; t++){
      float x = fl[(c*64 + t)*128 + sl];
      float nr = fmaf(lr, hr, fmaf(-li, hi2, x));
      float ni = fmaf(lr, hi2, li * hr);
      hr = nr; hi2 = ni;
    }
    ends[((size_t)(b*NCH + chunk))*SS + s] = make_float2(hr, hi2);
  }
}

// =================== mlp_fused v7: a-reads + stage hoisted ABOVE the vmcnt wait ===================
// (r22 diagnosis: per-k-step ~1700cyc vs ~80cyc MFMA; the sched_barrier after the
// vmcnt wait forced the INDEPENDENT Z1T/Y LDS a-reads and the next stage-issue
// into the post-stall serial chain. Reorder: {a-reads; stage(kt+2); vmcnt(4);
// sched_barrier; b-reads; MFMA}. Derived: after stage(kt+2), outstanding =
// {kt,kt+1,kt+2} = 6 loads -> vmcnt(4) completes kt, keeps 2 stages in flight.
// Tails: vmcnt(2) (kt+1 last staged), vmcnt(0).)
#define RING_OFF 65536

__global__ __launch_bounds__(1024, 1) void mlp_fused(
    const unsigned short* __restrict__ yH,
    const unsigned short* __restrict__ inH, const unsigned short* __restrict__ inL,
    const unsigned short* __restrict__ W1H, const unsigned short* __restrict__ W2H,
    const unsigned short* __restrict__ W3H, const unsigned short* __restrict__ W3L,
    const unsigned short* __restrict__ WlH, const unsigned short* __restrict__ WlL,
    float* __restrict__ out)
{
  __shared__ __align__(16) unsigned char LDS[163840];   // 160 KB
  const int tid = threadIdx.x;
  const int l = tid & 63, w = tid >> 6;      // 16 waves
  const int fr = l & 15, fq = l >> 4;
  const int mh = w >> 3, nf = w & 7;         // phase A2/C mapping
  const size_t r0 = (size_t)blockIdx.x * 64;
  const int ringb = RING_OFF + w*6144;

  // ---- 32-row stage (W1 / W2): rows w*32..+32, 2 GLD/thread ----
  auto stage32 = [&](const unsigned short* W, int strideK, int kt){
    const int so = (kt % 3) * 2048;
    #pragma unroll
    for (int it = 0; it < 2; it++){
      int seg = l + (it << 6);               // [32 rows][4 chunks]
      int r = seg >> 2, c4 = seg & 3;
      GLD16(W + (size_t)(w*32 + r) * strideK + kt*32 + ((c4 ^ ((r >> 1) & 3)) << 3),
            LDS + ringb + so + seg*16);
    }
  };
  // ---- H+L pair stage (Wl / W3): rows nf*16..+16, 2 planes, 2 GLD/thread ----
  auto stagePair = [&](const unsigned short* PH, const unsigned short* PL, int strideK, int kt){
    const int so = (kt % 3) * 2048;
    #pragma unroll
    for (int it = 0; it < 2; it++){
      int seg = l + (it << 6);               // [2 planes][16 rows][4 chunks]
      const unsigned short* P = (seg >> 6) ? PL : PH;
      int rr = (seg >> 2) & 15, c4 = seg & 3;
      GLD16(P + (size_t)(nf*16 + rr) * strideK + kt*32 + ((c4 ^ ((rr >> 1) & 3)) << 3),
            LDS + ringb + so + seg*16);
    }
  };

  // ---- prologue: stage Y@0, inH@16K, inL@32K (1 GLD each), W1 ring 0,1 ----
  {
    int r = tid >> 4, c16 = tid & 15;
    int sc = (c16 ^ (r & 7)) << 3;
    GLD16(yH  + (size_t)(r0 + r) * UU + sc, LDS + tid*16);
    GLD16(inH + (size_t)(r0 + r) * UU + sc, LDS + 16384 + tid*16);
    GLD16(inL + (size_t)(r0 + r) * UU + sc, LDS + 32768 + tid*16);
  }
  stage32(W1H, UU, 0);
  stage32(W1H, UU, 1);
  asm volatile("s_waitcnt vmcnt(4)" ::: "memory");   // Y/inH/inL (oldest) complete
  SBAR();                                    // [b1]

  f32x4 acc[4][2];
  #pragma unroll
  for (int m = 0; m < 4; m++)
    #pragma unroll
    for (int n = 0; n < 2; n++) acc[m][n] = f32x4{0.f, 0.f, 0.f, 0.f};

  // ======== phase A1: z1 = silu(y @ W1^T), 4 k-steps, barrier-free ========
  #pragma unroll
  for (int kt = 0; kt < 4; kt++){
    bf16x8 a[4], b[2];
    #pragma unroll
    for (int m = 0; m < 4; m++){             // a-reads: independent of staged W
      int row = m*16 + fr, kc = kt*4 + fq;
      a[m] = *(const bf16x8*)(LDS + (row*128 + ((kc ^ (row & 7)) << 3))*2);
    }
    if (kt + 2 < 4) stage32(W1H, UU, kt + 2);
    if (kt + 2 < 4)      asm volatile("s_waitcnt vmcnt(4)" ::: "memory");
    else if (kt + 1 < 4) asm volatile("s_waitcnt vmcnt(2)" ::: "memory");
    else                 asm volatile("s_waitcnt vmcnt(0)" ::: "memory");
    __builtin_amdgcn_sched_barrier(0);
    const unsigned char* Wb = LDS + ringb + (kt % 3)*2048;
    #pragma unroll
    for (int n = 0; n < 2; n++){
      int rl = n*16 + fr;
      b[n] = *(const bf16x8*)(Wb + rl*64 + ((fq ^ ((rl >> 1) & 3)) << 4));
    }
    __builtin_amdgcn_s_setprio(1);
    #pragma unroll
    for (int m = 0; m < 4; m++)
      #pragma unroll
      for (int n = 0; n < 2; n++)
        acc[m][n] = __builtin_amdgcn_mfma_f32_16x16x32_bf16(a[m], b[n], acc[m][n], 0, 0, 0);
    __builtin_amdgcn_s_setprio(0);
  }

  // ======== phase A2: acc_o = in @ Wl^T (3-term), 4 k-steps, barrier-free ========
  f32x4 acc_o[2];
  acc_o[0] = f32x4{0.f, 0.f, 0.f, 0.f};
  acc_o[1] = f32x4{0.f, 0.f, 0.f, 0.f};
  stagePair(WlH, WlL, UU, 0);
  stagePair(WlH, WlL, UU, 1);
  #pragma unroll
  for (int kt = 0; kt < 4; kt++){
    bf16x8 ah[2], al[2], bh, bl;
    #pragma unroll
    for (int m = 0; m < 2; m++){             // a-reads: independent of staged W
      int row = mh*32 + m*16 + fr, kc = kt*4 + fq;
      int off = (row*128 + ((kc ^ (row & 7)) << 3))*2;
      ah[m] = *(const bf16x8*)(LDS + 16384 + off);
      al[m] = *(const bf16x8*)(LDS + 32768 + off);
    }
    if (kt + 2 < 4) stagePair(WlH, WlL, UU, kt + 2);
    if (kt + 2 < 4)      asm volatile("s_waitcnt vmcnt(4)" ::: "memory");
    else if (kt + 1 < 4) asm volatile("s_waitcnt vmcnt(2)" ::: "memory");
    else                 asm volatile("s_waitcnt vmcnt(0)" ::: "memory");
    __builtin_amdgcn_sched_barrier(0);
    const unsigned char* Wb = LDS + ringb + (kt % 3)*2048;
    {
      int rl = fr;
      int boff = rl*64 + ((fq ^ ((rl >> 1) & 3)) << 4);
      bh = *(const bf16x8*)(Wb + boff);
      bl = *(const bf16x8*)(Wb + 1024 + boff);
    }
    __builtin_amdgcn_s_setprio(1);
    #pragma unroll
    for (int m = 0; m < 2; m++){
      acc_o[m] = __builtin_amdgcn_mfma_f32_16x16x32_bf16(ah[m], bh, acc_o[m], 0, 0, 0);
      acc_o[m] = __builtin_amdgcn_mfma_f32_16x16x32_bf16(al[m], bh, acc_o[m], 0, 0, 0);
      acc_o[m] = __builtin_amdgcn_mfma_f32_16x16x32_bf16(ah[m], bl, acc_o[m], 0, 0, 0);
    }
    __builtin_amdgcn_s_setprio(0);
  }
  SBAR();                                    // [b2] all Y/in reads done

  // W2 prologue stages (wave-private; latency hides under z1 silu/writes)
  stage32(W2H, HH, 0);
  stage32(W2H, HH, 1);

  // ---- silu + write z1 -> Z1T [kchunk][row][8] (K-major) @0 ----
  unsigned short* Z1 = (unsigned short*)LDS;
  #pragma unroll
  for (int m = 0; m < 4; m++)
    #pragma unroll
    for (int n = 0; n < 2; n++)
      #pragma unroll
      for (int j = 0; j < 4; j++){
        float x = acc[m][n][j];
        x = x / (1.f + __expf(-x));          // silu
        int row = m*16 + fq*4 + j;
        int col = w*32 + n*16 + fr;
        Z1[(col >> 3)*512 + row*8 + (col & 7)] = f2bf(x);
      }
  SBAR();                                    // [b3] z1 visible

  // ======== phase B: z2 = relu(z1 @ W2^T), 16 k-steps, barrier-free ========
  #pragma unroll
  for (int m = 0; m < 4; m++)
    #pragma unroll
    for (int n = 0; n < 2; n++) acc[m][n] = f32x4{0.f, 0.f, 0.f, 0.f};

  #pragma unroll
  for (int kt = 0; kt < 16; kt++){
    bf16x8 a[4], b[2];
    #pragma unroll
    for (int m = 0; m < 4; m++)              // a-reads: Z1T, independent
      a[m] = *(const bf16x8*)(LDS + (size_t)(kt*4 + fq)*1024 + (m*16 + fr)*16);
    if (kt + 2 < 16) stage32(W2H, HH, kt + 2);
    if (kt + 2 < 16)      asm volatile("s_waitcnt vmcnt(4)" ::: "memory");
    else if (kt + 1 < 16) asm volatile("s_waitcnt vmcnt(2)" ::: "memory");
    else                  asm volatile("s_waitcnt vmcnt(0)" ::: "memory");
    __builtin_amdgcn_sched_barrier(0);
    const unsigned char* Wb = LDS + ringb + (kt % 3)*2048;
    #pragma unroll
    for (int n = 0; n < 2; n++){
      int rl = n*16 + fr;
      b[n] = *(const bf16x8*)(Wb + rl*64 + ((fq ^ ((rl >> 1) & 3)) << 4));
    }
    __builtin_amdgcn_s_setprio(1);
    #pragma unroll
    for (int m = 0; m < 4; m++)
      #pragma unroll
      for (int n = 0; n < 2; n++)
        acc[m][n] = __builtin_amdgcn_mfma_f32_16x16x32_bf16(a[m], b[n], acc[m][n], 0, 0, 0);
    __builtin_amdgcn_s_setprio(0);
  }

  // W3 prologue stages (own ring, freed by vmcnt(0) above)
  stagePair(W3H, W3L, HH, 0);
  stagePair(W3H, W3L, HH, 1);
  SBAR();                                    // [b4] all Z1T reads done

  // ---- relu + write z2 -> Z2T [kchunk][row][8] @0 (bf16 rounding as before) ----
  unsigned short* Z2 = (unsigned short*)LDS;
  #pragma unroll
  for (int m = 0; m < 4; m++)
    #pragma unroll
    for (int n = 0; n < 2; n++)
      #pragma unroll
      for (int j = 0; j < 4; j++){
        float x = fmaxf(acc[m][n][j], 0.f);  // relu
        int row = m*16 + fq*4 + j;
        int col = w*32 + n*16 + fr;
        Z2[(col >> 3)*512 + row*8 + (col & 7)] = f2bf(x);
      }
  SBAR();                                    // [b5] z2 visible

  // ======== phase C: acc_o += z2 @ W3^T (2-term), 16 k-steps, barrier-free ========
  #pragma unroll
  for (int kt = 0; kt < 16; kt++){
    bf16x8 a[2], bh, bl;
    #pragma unroll
    for (int m = 0; m < 2; m++)              // a-reads: Z2T, independent
      a[m] = *(const bf16x8*)(LDS + (size_t)(kt*4 + fq)*1024 + (mh*32 + m*16 + fr)*16);
    if (kt + 2 < 16) stagePair(W3H, W3L, HH, kt + 2);
    if (kt + 2 < 16)      asm volatile("s_waitcnt vmcnt(4)" ::: "memory");
    else if (kt + 1 < 16) asm volatile("s_waitcnt vmcnt(2)" ::: "memory");
    else                  asm volatile("s_waitcnt vmcnt(0)" ::: "memory");
    __builtin_amdgcn_sched_barrier(0);
    const unsigned char* Wb = LDS + ringb + (kt % 3)*2048;
    {
      int rl = fr;
      int boff = rl*64 + ((fq ^ ((rl >> 1) & 3)) << 4);
      bh = *(const bf16x8*)(Wb + boff);
      bl = *(const bf16x8*)(Wb + 1024 + boff);
    }
    __builtin_amdgcn_s_setprio(1);
    #pragma unroll
    for (int m = 0; m < 2; m++){
      acc_o[m] = __builtin_amdgcn_mfma_f32_16x16x32_bf16(a[m], bh, acc_o[m], 0, 0, 0);
      acc_o[m] = __builtin_amdgcn_mfma_f32_16x16x32_bf16(a[m], bl, acc_o[m], 0, 0, 0);
    }
    __builtin_amdgcn_s_setprio(0);
  }
  SBAR();                                    // [b6] rings free for EP reuse

  // ---- fp32 epilogue via LDS (64x128 f32 = 32 KB @RING_OFF) ----
  float* EP = (float*)(LDS + RING_OFF);
  #pragma unroll
  for (int m = 0; m < 2; m++)
    #pragma unroll
    for (int j = 0; j < 4; j++)
      EP[(mh*32 + m*16 + fq*4 + j)*128 + nf*16 + fr] = acc_o[m][j];
  __syncthreads();
  #pragma unroll
  for (int it = 0; it < 2; it++){
    int seg = tid + (it << 10);              // 2048 float4 = [64 rows][32 groups]
    int r = seg >> 5, c4 = seg & 31;
    *(float4*)(out + (r0 + r)*OO + c4*4) = *(const float4*)(EP + r*128 + c4*4);
  }
}

// ---------------- scan carries ----------------
__global__ __launch_bounds__(256) void scan_carries(const float2* __restrict__ ends,
                                                    const float* __restrict__ lre,
                                                    const float* __restrict__ lim,
                                                    float2* __restrict__ carryin){
  const int idx = blockIdx.x * 256 + threadIdx.x;
  const int b = idx >> 8;
  const int s = idx & 255;
  float pr = lre[s], pi = lim[s];
  #pragma unroll
  for (int q = 0; q < 6; q++){
    float nr = pr*pr - pi*pi;
    float ni = 2.f * pr * pi;
    pr = nr; pi = ni;
  }
  float hr = 0.f, hi = 0.f;
  for (int c = 0; c < NCH; c++){
    size_t o = ((size_t)b*NCH + c)*SS + s;
    carryin[o] = make_float2(hr, hi);
    float2 e = ends[o];
    float nr = fmaf(pr, hr, fmaf(-pi, hi, e.x));
    float ni = fmaf(pr, hi, fmaf(pi, hr, e.y));
    hr = nr; hi = ni;
  }
}

// ---------------- scan apply: vectorized, RehH (bf16) only ----------------
__global__ __launch_bounds__(256) void scan_apply_v(
    const unsigned short* __restrict__ buH, const unsigned short* __restrict__ buL,
    const float* __restrict__ lre, const float* __restrict__ lim,
    const float2* __restrict__ carryin, unsigned short* __restrict__ RehH){
  const int tid = threadIdx.x;
  const int grp = tid >> 6, ln = tid & 63;
  const int chunk = blockIdx.x * 4 + grp;         // 0..1023
  const int b = chunk >> 6, ch = chunk & 63;
  const int s0 = ln * 4;
  float lr[4], li[4], hr[4], hi[4];
  #pragma unroll
  for (int e = 0; e < 4; e++){ lr[e] = lre[s0+e]; li[e] = lim[s0+e]; }
  const float2* ci = &carryin[((size_t)(b*NCH + ch))*SS + s0];
  #pragma unroll
  for (int e = 0; e < 4; e++){ hr[e] = ci[e].x; hi[e] = ci[e].y; }
  const size_t rbase = ((size_t)b*TT + (size_t)ch*CLEN)*SS + s0;
  for (int t = 0; t < CLEN; t++){
    uint2 hv = *(const uint2*)(buH + rbase + (size_t)t*SS);
    uint2 lv = *(const uint2*)(buL + rbase + (size_t)t*SS);
    const unsigned short* hs = (const unsigned short*)&hv;
    const unsigned short* ls = (const unsigned short*)&lv;
    uint2 ov; unsigned short* os = (unsigned short*)&ov;
    #pragma unroll
    for (int e = 0; e < 4; e++){
      float x = bf2f(hs[e]) + bf2f(ls[e]);
      float nr = fmaf(lr[e], hr[e], fmaf(-li[e], hi[e], x));
      float ni = fmaf(lr[e], hi[e], li[e] * hr[e]);
      hr[e] = nr; hi[e] = ni;
      os[e] = f2bf(nr);
    }
    *(uint2*)(RehH + rbase + (size_t)t*SS) = ov;
  }
}

extern "C" void kernel_launch(void* const* d_in, const int* in_sizes, int n_in,
                              void* d_out, int out_size, void* d_ws, size_t ws_size,
                              hipStream_t stream){
  const float* inp = (const float*)d_in[0];
  const float* lre = (const float*)d_in[1];
  const float* lim = (const float*)d_in[2];
  const float* Bm  = (const float*)d_in[3];
  const float* Cm  = (const float*)d_in[4];
  const float* Dm  = (const float*)d_in[5];
  const float* W1  = (const float*)d_in[6];
  const float* W2  = (const float*)d_in[7];
  const float* W3  = (const float*)d_in[8];
  const float* Wl  = (const float*)d_in[9];
  float* out = (float*)d_out;

  char* ws = (char*)d_ws;
  size_t off = 0;
  auto alloc = [&](size_t bytes)->char*{
    char* p = ws + off; off += (bytes + 255) & ~(size_t)255; return p;
  };
  // ---- region-reused workspace plan ----
  unsigned short* inH  = (unsigned short*)alloc((size_t)BT*UU*2);   // live all
  unsigned short* inL  = (unsigned short*)alloc((size_t)BT*UU*2);   // live all
  char* Rbu = alloc((size_t)BT*SS*2*2);                             // buH+buL
  unsigned short* buH = (unsigned short*)Rbu;
  unsigned short* buL = (unsigned short*)(Rbu + (size_t)BT*SS*2);
  char* R2 = alloc((size_t)BT*HH*2);                                // RehH+yH
  unsigned short* RehH = (unsigned short*)R2;
  unsigned short* yH   = (unsigned short*)(R2 + (size_t)BT*SS*2);
  unsigned short* BwH = (unsigned short*)alloc((size_t)SS*UU*2);
  unsigned short* BwL = (unsigned short*)alloc((size_t)SS*UU*2);
  unsigned short* CH_ = (unsigned short*)alloc((size_t)OO*SS*2);
  unsigned short* CL_ = (unsigned short*)alloc((size_t)OO*SS*2);
  unsigned short* DH_ = (unsigned short*)alloc((size_t)OO*UU*2);
  unsigned short* DL_ = (unsigned short*)alloc((size_t)OO*UU*2);
  unsigned short* W1H = (unsigned short*)alloc((size_t)HH*OO*2);
  unsigned short* W1L = (unsigned short*)alloc((size_t)HH*OO*2);
  unsigned short* W2H = (unsigned short*)alloc((size_t)HH*HH*2);
  unsigned short* W2L = (unsigned short*)alloc((size_t)HH*HH*2);
  unsigned short* W3H = (unsigned short*)alloc((size_t)OO*HH*2);
  unsigned short* W3L = (unsigned short*)alloc((size_t)OO*HH*2);
  unsigned short* WlH = (unsigned short*)alloc((size_t)OO*UU*2);
  unsigned short* WlL = (unsigned short*)alloc((size_t)OO*UU*2);
  float2* ends    = (float2*)alloc((size_t)BSZ*NCH*SS*8);
  float2* carryin = (float2*)alloc((size_t)BSZ*NCH*SS*8);
  if (off > ws_size) return;

  // ---- splits ----
  split_k<<<(BT*UU/4 + 255)/256, 256, 0, stream>>>(inp, inH, inL, BT*UU/4);
  {
    WJobs j;
    const float* srcs[7] = {Bm, Cm, Dm, W1, W2, W3, Wl};
    unsigned short* Hs[7] = {BwH, CH_, DH_, W1H, W2H, W3H, WlH};
    unsigned short* Ls[7] = {BwL, CL_, DL_, W1L, W2L, W3L, WlL};
    int n4s[7] = {SS*UU/4, OO*SS/4, OO*UU/4, HH*OO/4, HH*HH/4, OO*HH/4, OO*UU/4};
    int cum = 0;
    for (int k = 0; k < 7; k++){
      j.src[k] = srcs[k]; j.H[k] = Hs[k]; j.L[k] = Ls[k];
      cum += n4s[k]; j.end4[k] = cum;
    }
    split_w<<<(cum + 255)/256, 256, 0, stream>>>(j, cum);
  }

  // ---- bu = input @ B^T (3-term), H/L out + fused chunk-end scans ----
  gemm_split<<<dim3(BT/128, SS/128), 256, 0, stream>>>(
      inH, inL, BwH, BwL, UU, 3,
      inH, inL, BwH, BwL, 0,  3,
      buH, buL, nullptr, SS, 1,
      lre, lim, ends);

  // ---- cross-chunk carries ----
  scan_carries<<<(BSZ*SS)/256, 256, 0, stream>>>(ends, lre, lim, carryin);

  // ---- scan apply -> RehH (bf16 only) ----
  scan_apply_v<<<BSZ*NCH/4, 256, 0, stream>>>(buH, buL, lre, lim, carryin, RehH);

  // ---- y = Reh@C^T (2-term: C hi+lo) + in@D^T (3-term); yH only ----
  gemm_split<<<dim3(BT/128, OO/128), 256, 0, stream>>>(
      RehH, RehH, CH_, CL_, SS, 2,
      inH,  inL,  DH_, DL_, UU, 3,
      yH, nullptr, nullptr, OO, 1,
      nullptr, nullptr, nullptr);

  // ---- out = relu(silu(y@W1^T)@W2^T)@W3^T + in@Wl^T : fully fused ----
  mlp_fused<<<BT/64, 1024, 0, stream>>>(yH, inH, inL, W1H, W2H, W3H, W3L,
                                        WlH, WlL, out);
}